// Round 4
// baseline (1953.799 us; speedup 1.0000x reference)
//
#include <hip/hip_runtime.h>
#include <stdint.h>

using u16 = unsigned short;
using u32 = unsigned int;

typedef short bf8_t __attribute__((ext_vector_type(8)));   // 8 bf16 values (4 VGPRs)
typedef float f4_t  __attribute__((ext_vector_type(4)));

// ---------- helpers ----------
__device__ __forceinline__ u16 f2bf(float f) {
  u32 u = __float_as_uint(f);
  u32 r = (u + 0x7FFFu + ((u >> 16) & 1u)) >> 16;   // RNE
  return (u16)r;
}

__device__ __forceinline__ void cp16(const void* g, void* l) {
  // async global->LDS, 16B per lane; LDS dest = wave-uniform base + lane*16
  __builtin_amdgcn_global_load_lds(
      (const __attribute__((address_space(1))) u32*)g,
      (__attribute__((address_space(3))) u32*)l, 16, 0, 0);
}

// JAX threefry2x32, key = (0, 42)  [jax.random.key(42)]
__device__ __forceinline__ void threefry_0_42(u32 x0, u32 x1, u32& o0, u32& o1) {
  const u32 k0 = 0u, k1 = 42u;
  const u32 k2 = 0x1BD11BDAu ^ k0 ^ k1;
#define TFR(r) { x0 += x1; x1 = (x1 << r) | (x1 >> (32 - r)); x1 ^= x0; }
  x0 += k0; x1 += k1;
  TFR(13) TFR(15) TFR(26) TFR(6)   x0 += k1; x1 += k2 + 1u;
  TFR(17) TFR(29) TFR(16) TFR(24)  x0 += k2; x1 += k0 + 2u;
  TFR(13) TFR(15) TFR(26) TFR(6)   x0 += k0; x1 += k1 + 3u;
  TFR(17) TFR(29) TFR(16) TFR(24)  x0 += k1; x1 += k2 + 4u;
  TFR(13) TFR(15) TFR(26) TFR(6)   x0 += k2; x1 += k0 + 5u;
#undef TFR
  o0 = x0; o1 = x1;
}

// ---------- conversion / padding ----------
__global__ __launch_bounds__(256)
void cvt_bf16(const float* __restrict__ s, u16* __restrict__ d, int n4) {
  const int i = blockIdx.x * 256 + threadIdx.x;
  if (i >= n4) return;
  const float4 v = ((const float4*)s)[i];
  ushort4 o;
  o.x = f2bf(v.x); o.y = f2bf(v.y); o.z = f2bf(v.z); o.w = f2bf(v.w);
  ((ushort4*)d)[i] = o;
}

__global__ __launch_bounds__(256)
void pad_cls(const float* __restrict__ src, u16* __restrict__ dst) {
  const int i = blockIdx.x * 256 + threadIdx.x;      // 32*2048
  const int row = i >> 11, col = i & 2047;
  dst[i] = (row < 21) ? f2bf(src[row * 2048 + col]) : (u16)0;
}

__global__ __launch_bounds__(256)
void pad_head(const float* __restrict__ cf, const float* __restrict__ mk,
              u16* __restrict__ dst) {
  const int i = blockIdx.x * 256 + threadIdx.x;      // 32*1024
  const int row = i >> 10, col = i & 1023;
  float v = 0.0f;
  if (row < 22)      v = cf[row * 1024 + col];
  else if (row < 24) v = mk[(row - 22) * 1024 + col];
  dst[i] = f2bf(v);
}

// zero h buffer (t=0 reads it) + the device-barrier counter (ws is poisoned 0xAA
// before every timed launch, so this kernel re-inits every call)
__global__ __launch_bounds__(256)
void init_h(u16* __restrict__ hbf, u32* __restrict__ barrier_cnt) {
  const int i = blockIdx.x * 256 + threadIdx.x;      // 128*1024
  hbf[i] = 0;
  if (i == 0) *barrier_cnt = 0u;
}

// ---------- big GEMM: C[M,N] = A[M,K] * B[N,K]^T (+bias, opt relu) ----------
// 128x128 tile, BK=64, 256 threads (4 waves as 2x2 of 64x64)
template<int RELU>
__global__ __launch_bounds__(256)
void gemm128(const u16* __restrict__ A, const u16* __restrict__ Bw,
             const float* __restrict__ bias, float* __restrict__ C,
             int N, int K) {
  __shared__ __align__(16) u16 As[128 * 64];
  __shared__ __align__(16) u16 Bs[128 * 64];
  const int tid = threadIdx.x;
  const int wv = tid >> 6, lane = tid & 63;
  const int wm = wv >> 1, wn = wv & 1;
  const u16* Ab = A + (size_t)blockIdx.x * 128 * K;
  const u16* Bb = Bw + (size_t)blockIdx.y * 128 * K;
  const int lr = lane >> 3, lc = lane & 7;
  f4_t acc[4][4] = {};
  for (int k0 = 0; k0 < K; k0 += 64) {
#pragma unroll
    for (int i = 0; i < 4; ++i) {
      const int row = wv * 32 + i * 8;
      cp16(Ab + (size_t)(row + lr) * K + (k0 + lc * 8), &As[row * 64]);
      cp16(Bb + (size_t)(row + lr) * K + (k0 + lc * 8), &Bs[row * 64]);
    }
    __syncthreads();
#pragma unroll
    for (int kk = 0; kk < 2; ++kk) {
      bf8_t av[4], bv[4];
#pragma unroll
      for (int mt = 0; mt < 4; ++mt)
        av[mt] = *(const bf8_t*)&As[(wm * 64 + mt * 16 + (lane & 15)) * 64 + kk * 32 + (lane >> 4) * 8];
#pragma unroll
      for (int nt = 0; nt < 4; ++nt)
        bv[nt] = *(const bf8_t*)&Bs[(wn * 64 + nt * 16 + (lane & 15)) * 64 + kk * 32 + (lane >> 4) * 8];
#pragma unroll
      for (int mt = 0; mt < 4; ++mt)
#pragma unroll
        for (int nt = 0; nt < 4; ++nt)
          acc[mt][nt] = __builtin_amdgcn_mfma_f32_16x16x32_bf16(av[mt], bv[nt], acc[mt][nt], 0, 0, 0);
    }
    __syncthreads();
  }
  const int q = lane >> 4, cn = lane & 15;
#pragma unroll
  for (int mt = 0; mt < 4; ++mt) {
#pragma unroll
    for (int nt = 0; nt < 4; ++nt) {
      const int col = blockIdx.y * 128 + wn * 64 + nt * 16 + cn;
      const float bb = bias[col];
#pragma unroll
      for (int r = 0; r < 4; ++r) {
        const int row = blockIdx.x * 128 + wm * 64 + mt * 16 + q * 4 + r;
        float v = acc[mt][nt][r] + bb;
        if (RELU) v = fmaxf(v, 0.0f);
        C[(size_t)row * N + col] = v;
      }
    }
  }
}

// ---------- skinny GEMM: C[M,32] = A[M,K] * B[32,K]^T, M-tile 64 ----------
// HEAD=0: vl_preds (cols<21, +cls_b). HEAD=1: enc (cols<22,+cf_b) / mask (cols 22..23,+mk_b)
template<int HEAD>
__global__ __launch_bounds__(256)
void gemm_skinny(const u16* __restrict__ A, const u16* __restrict__ Bw,
                 const float* __restrict__ bias, const float* __restrict__ bias2,
                 float* __restrict__ C0, float* __restrict__ C1, int K) {
  __shared__ __align__(16) u16 As[64 * 64];
  __shared__ __align__(16) u16 Bs[32 * 64];
  const int tid = threadIdx.x, wv = tid >> 6, lane = tid & 63;
  const u16* Ab = A + (size_t)blockIdx.x * 64 * K;
  const int lr = lane >> 3, lc = lane & 7;
  f4_t acc[2] = {};
  for (int k0 = 0; k0 < K; k0 += 64) {
#pragma unroll
    for (int i = 0; i < 2; ++i) {
      const int row = wv * 16 + i * 8;
      cp16(Ab + (size_t)(row + lr) * K + (k0 + lc * 8), &As[row * 64]);
    }
    {
      const int row = wv * 8;
      cp16(Bw + (size_t)(row + lr) * K + (k0 + lc * 8), &Bs[row * 64]);
    }
    __syncthreads();
#pragma unroll
    for (int kk = 0; kk < 2; ++kk) {
      bf8_t a = *(const bf8_t*)&As[(wv * 16 + (lane & 15)) * 64 + kk * 32 + (lane >> 4) * 8];
#pragma unroll
      for (int nt = 0; nt < 2; ++nt) {
        bf8_t b = *(const bf8_t*)&Bs[(nt * 16 + (lane & 15)) * 64 + kk * 32 + (lane >> 4) * 8];
        acc[nt] = __builtin_amdgcn_mfma_f32_16x16x32_bf16(a, b, acc[nt], 0, 0, 0);
      }
    }
    __syncthreads();
  }
  const int q = lane >> 4, cn = lane & 15;
#pragma unroll
  for (int nt = 0; nt < 2; ++nt) {
    const int col = nt * 16 + cn;
#pragma unroll
    for (int r = 0; r < 4; ++r) {
      const int row = blockIdx.x * 64 + wv * 16 + q * 4 + r;
      const float v = acc[nt][r];
      if (HEAD) {
        if (col < 22)      C0[(size_t)row * 22 + col] = v + bias[col];
        else if (col < 24) C1[(size_t)row * 2 + (col - 22)] = v + bias2[col - 22];
      } else {
        if (col < 21)      C0[(size_t)row * 21 + col] = v + bias[col];
      }
    }
  }
}

// ---------- dropout: JAX partitionable threefry bernoulli, key 42, p_keep=0.7 ----------
// bits = o0 ^ o1 of threefry2x32((0,42), (0, j))  [verified R3: absmax 0.031 PASS]
__global__ __launch_bounds__(256)
void dropout_kernel(float* __restrict__ x, u16* __restrict__ xbf) {
  const u32 tid = blockIdx.x * 256u + threadIdx.x;   // 2^22 threads
  const u32 j0 = tid * 4u;
  float4 a = *(const float4*)(x + j0);
  float av[4] = {a.x, a.y, a.z, a.w};
  u16 abf[4];
#pragma unroll
  for (int i = 0; i < 4; ++i) {
    u32 o0, o1;
    threefry_0_42(0u, j0 + (u32)i, o0, o1);
    const u32 bits = o0 ^ o1;
    const float u1 = __uint_as_float((bits >> 9) | 0x3f800000u) - 1.0f;
    av[i] = (u1 < 0.7f) ? av[i] * (1.0f / 0.7f) : 0.0f;
    abf[i] = f2bf(av[i]);
  }
  float4 oa; oa.x = av[0]; oa.y = av[1]; oa.z = av[2]; oa.w = av[3];
  *(float4*)(x + j0) = oa;
  ushort4 ua; ua.x = abf[0]; ua.y = abf[1]; ua.z = abf[2]; ua.w = abf[3];
  *(ushort4*)(xbf + j0) = ua;
}

// ---------- persistent GRU: all 64 steps in ONE kernel ----------
// 256 blocks x 256 threads, 1 block/CU (LDS ~124 KB), all co-resident.
// Block (cb = blockIdx.x & 63, sb = blockIdx.x >> 6): 16 hid cols, 32 seqs.
// whh slab [48 rows x 1024] staged in LDS ONCE (row pad -> 1032 halves: b-frag
// ds_read_b128 lands 2-way on banks, which is free per m136).
// Waves split K (256 each); partial G reduced via LDS; fp32 h lives in regs
// (2 values/thread). One device-scope barrier per step; h bf16 double-buffered.
#define GRU_BLOCKS 256
__global__ __launch_bounds__(256, 1)
void gru_persistent(const u16* __restrict__ whh, const float* __restrict__ gi,
                    const float* __restrict__ bhh, u16* __restrict__ hbuf0,
                    u16* __restrict__ hbuf1, u16* __restrict__ hrbf,
                    u32* barrier_cnt) {
  __shared__ __align__(16) u16 Ws[48 * 1032];        // 99,072 B
  __shared__ float Gs[4][32 * 49];                   // 25,088 B (row pad 49: quad offsets hit distinct banks)
  const int tid = threadIdx.x, wv = tid >> 6, lane = tid & 63;
  const int cb = blockIdx.x & 63, sb = blockIdx.x >> 6;
  const int col0 = cb * 16, seq0 = sb * 32;

  // ---- stage whh slab (local rows: 0-15 r-gate, 16-31 z, 32-47 n) ----
  for (int i = tid; i < 48 * 128; i += 256) {        // 16B chunks
    const int row = i >> 7, ch = i & 127;
    const int grow = (row >> 4) * 1024 + col0 + (row & 15);
    const uint4 v = *(const uint4*)(whh + (size_t)grow * 1024 + ch * 8);
    *(uint4*)&Ws[row * 1032 + ch * 8] = v;
  }

  // ---- per-thread persistent state ----
  const int j = tid & 15;                            // col within tile
  const int mA = tid >> 4, mB = 16 + (tid >> 4);     // two seq rows
  const int col = col0 + j;
  const int seqA = seq0 + mA, seqB = seq0 + mB;
  float hA = 0.0f, hB = 0.0f;                        // fp32 h master copy (regs)
  const float bR = bhh[col], bZ = bhh[1024 + col], bN = bhh[2048 + col];
  const size_t gbA = ((size_t)((seqA >> 3) * 512 + (seqA & 7) * 64)) * 3072 + col;
  const size_t gbB = ((size_t)((seqB >> 3) * 512 + (seqB & 7) * 64)) * 3072 + col;
  const int la15 = lane & 15, la16 = lane >> 4;
  __syncthreads();

  for (int t = 0; t < 64; ++t) {
    const u16* __restrict__ hread = (t & 1) ? hbuf1 : hbuf0;
    u16* __restrict__ hwrite      = (t & 1) ? hbuf0 : hbuf1;
    // ---- G partial = h[32 x k-slice] @ Ws^T, K split across waves ----
    f4_t acc[2][3] = {};
    const int kbase = wv * 256;
#pragma unroll
    for (int kc = 0; kc < 8; ++kc) {
      const int k = kbase + kc * 32;
      bf8_t a0 = *(const bf8_t*)(hread + (size_t)(seq0 + la15) * 1024 + k + la16 * 8);
      bf8_t a1 = *(const bf8_t*)(hread + (size_t)(seq0 + 16 + la15) * 1024 + k + la16 * 8);
#pragma unroll
      for (int nt = 0; nt < 3; ++nt) {
        bf8_t b = *(const bf8_t*)&Ws[(nt * 16 + la15) * 1032 + k + la16 * 8];
        acc[0][nt] = __builtin_amdgcn_mfma_f32_16x16x32_bf16(a0, b, acc[0][nt], 0, 0, 0);
        acc[1][nt] = __builtin_amdgcn_mfma_f32_16x16x32_bf16(a1, b, acc[1][nt], 0, 0, 0);
      }
    }
    // ---- stash partials (C layout: col=lane&15, row=quad*4+r) ----
#pragma unroll
    for (int mt = 0; mt < 2; ++mt)
#pragma unroll
      for (int nt = 0; nt < 3; ++nt)
#pragma unroll
        for (int r = 0; r < 4; ++r)
          Gs[wv][(mt * 16 + la16 * 4 + r) * 49 + nt * 16 + la15] = acc[mt][nt][r];
    __syncthreads();
    // ---- reduce 4 wave-partials + gate math, 2 (seq,col) items/thread ----
#pragma unroll
    for (int p = 0; p < 2; ++p) {
      const int m = p ? mB : mA;
      const float* g0 = &Gs[0][m * 49 + j];
      float Gr = g0[0] + (&Gs[1][0])[m * 49 + j] + (&Gs[2][0])[m * 49 + j] + (&Gs[3][0])[m * 49 + j];
      float Gz = g0[16] + (&Gs[1][0])[m * 49 + 16 + j] + (&Gs[2][0])[m * 49 + 16 + j] + (&Gs[3][0])[m * 49 + 16 + j];
      float Gn = g0[32] + (&Gs[1][0])[m * 49 + 32 + j] + (&Gs[2][0])[m * 49 + 32 + j] + (&Gs[3][0])[m * 49 + 32 + j];
      const size_t gb = (p ? gbB : gbA) + (size_t)t * 3072;
      const float gr = Gr + bR + gi[gb];
      const float gz = Gz + bZ + gi[gb + 1024];
      const float gh = Gn + bN;                      // b_hh on n-gate is scaled by r
      const float gn = gi[gb + 2048];
      const float rr = 1.0f / (1.0f + __expf(-gr));
      const float zz = 1.0f / (1.0f + __expf(-gz));
      float targ = gn + rr * gh;
      targ = fminf(fmaxf(targ, -15.0f), 15.0f);
      const float e2 = __expf(2.0f * targ);
      const float nn = (e2 - 1.0f) / (e2 + 1.0f);
      const float hp = p ? hB : hA;
      const float h = (1.0f - zz) * nn + zz * hp;
      if (p) hB = h; else hA = h;
      const int seq = p ? seqB : seqA;
      hwrite[(size_t)seq * 1024 + col] = f2bf(h);
      hrbf[((size_t)t * 128 + seq) * 1024 + col] = f2bf(fmaxf(h, 0.0f));
    }
    // ---- device barrier (blocks all co-resident; cnt monotone, no reset) ----
    __syncthreads();                                 // drains vmcnt: h stores are in L2
    if (tid == 0) {
      __hip_atomic_fetch_add(barrier_cnt, 1u, __ATOMIC_ACQ_REL, __HIP_MEMORY_SCOPE_AGENT);
      const u32 target = (u32)(t + 1) * GRU_BLOCKS;
      while (__hip_atomic_load(barrier_cnt, __ATOMIC_ACQUIRE, __HIP_MEMORY_SCOPE_AGENT) < target)
        __builtin_amdgcn_s_sleep(1);
    }
    __syncthreads();
  }
}

// ---------- host ----------
extern "C" void kernel_launch(void* const* d_in, const int* in_sizes, int n_in,
                              void* d_out, int out_size, void* d_ws, size_t ws_size,
                              hipStream_t stream) {
  const float* feats = (const float*)d_in[0];
  const float* fc_w  = (const float*)d_in[1];
  const float* fc_b  = (const float*)d_in[2];
  const float* cls_w = (const float*)d_in[3];
  const float* cls_b = (const float*)d_in[4];
  const float* w_ih  = (const float*)d_in[5];
  const float* w_hh  = (const float*)d_in[6];
  const float* b_ih  = (const float*)d_in[7];
  const float* b_hh  = (const float*)d_in[8];
  const float* cf_w  = (const float*)d_in[9];
  const float* cf_b  = (const float*)d_in[10];
  const float* mk_w  = (const float*)d_in[11];
  const float* mk_b  = (const float*)d_in[12];

  char* ws = (char*)d_ws;
  size_t off = 0;
  auto alloc = [&](size_t b) { char* p = ws + off; off += (b + 255) & ~(size_t)255; return p; };
  u16*  featsbf = (u16*)alloc((size_t)8192 * 2048 * 2);
  u16*  xbf     = featsbf;                 // alias: feats_bf dead after fc GEMM
  u16*  fcwbf   = (u16*)alloc((size_t)2048 * 2048 * 2);
  u16*  wihbf   = (u16*)alloc((size_t)3072 * 2048 * 2);
  u16*  whhbf   = (u16*)alloc((size_t)3072 * 1024 * 2);
  u16*  clsp    = (u16*)alloc((size_t)32 * 2048 * 2);
  u16*  headp   = (u16*)alloc((size_t)32 * 1024 * 2);
  float* gi     = (float*)alloc((size_t)8192 * 3072 * 4);
  u16*  hbf0    = (u16*)alloc((size_t)128 * 1024 * 2);
  u16*  hbf1    = (u16*)alloc((size_t)128 * 1024 * 2);
  u16*  hrbf    = (u16*)alloc((size_t)8192 * 1024 * 2);
  u32*  barrier = (u32*)alloc(256);

  float* out_enc  = (float*)d_out;                       // [8192,22]
  float* out_mask = out_enc + (size_t)8192 * 22;         // [8192,2]
  float* out_x    = out_mask + (size_t)8192 * 2;         // [16,512,2048]
  float* out_vl   = out_x + (size_t)8192 * 2048;         // [16,512,21]

  cvt_bf16<<<16384, 256, 0, stream>>>(feats, featsbf, 4194304);
  cvt_bf16<<<4096, 256, 0, stream>>>(fc_w, fcwbf, 1048576);
  cvt_bf16<<<6144, 256, 0, stream>>>(w_ih, wihbf, 1572864);
  cvt_bf16<<<3072, 256, 0, stream>>>(w_hh, whhbf, 786432);
  pad_cls<<<256, 256, 0, stream>>>(cls_w, clsp);
  pad_head<<<128, 256, 0, stream>>>(cf_w, mk_w, headp);
  init_h<<<512, 256, 0, stream>>>(hbf0, barrier);

  // x_pre = relu(feats @ fc_w^T + fc_b) -> out_x (fp32)
  gemm128<1><<<dim3(64, 16), 256, 0, stream>>>(featsbf, fcwbf, fc_b, out_x, 2048, 2048);
  // in-place dropout on out_x; also writes bf16 x into ws
  dropout_kernel<<<16384, 256, 0, stream>>>(out_x, xbf);
  // vl_preds
  gemm_skinny<0><<<128, 256, 0, stream>>>(xbf, clsp, cls_b, nullptr, out_vl, nullptr, 2048);
  // gi = x @ w_ih^T + b_ih   (b_hh NOT folded: n-gate needs r*(gh+b_hh))
  gemm128<0><<<dim3(64, 24), 256, 0, stream>>>(xbf, wihbf, b_ih, gi, 3072, 2048);

  // all 64 GRU steps in one persistent kernel
  gru_persistent<<<GRU_BLOCKS, 256, 0, stream>>>(whhbf, gi, b_hh, hbf0, hbf1, hrbf, barrier);

  // heads: enc_scores + mask_scores
  gemm_skinny<1><<<128, 256, 0, stream>>>(hrbf, headp, cf_b, mk_b, out_enc, out_mask, 1024);
}

// Round 5
// 1332.050 us; speedup vs baseline: 1.4668x; 1.4668x over previous
//
#include <hip/hip_runtime.h>
#include <stdint.h>

using u16 = unsigned short;
using u32 = unsigned int;

typedef short bf8_t __attribute__((ext_vector_type(8)));   // 8 bf16 values (4 VGPRs)
typedef float f4_t  __attribute__((ext_vector_type(4)));

// ---------- helpers ----------
__device__ __forceinline__ u16 f2bf(float f) {
  u32 u = __float_as_uint(f);
  u32 r = (u + 0x7FFFu + ((u >> 16) & 1u)) >> 16;   // RNE
  return (u16)r;
}

__device__ __forceinline__ void cp16(const void* g, void* l) {
  // async global->LDS, 16B per lane; LDS dest = wave-uniform base + lane*16
  __builtin_amdgcn_global_load_lds(
      (const __attribute__((address_space(1))) u32*)g,
      (__attribute__((address_space(3))) u32*)l, 16, 0, 0);
}

// JAX threefry2x32, key = (0, 42)  [jax.random.key(42)]
__device__ __forceinline__ void threefry_0_42(u32 x0, u32 x1, u32& o0, u32& o1) {
  const u32 k0 = 0u, k1 = 42u;
  const u32 k2 = 0x1BD11BDAu ^ k0 ^ k1;
#define TFR(r) { x0 += x1; x1 = (x1 << r) | (x1 >> (32 - r)); x1 ^= x0; }
  x0 += k0; x1 += k1;
  TFR(13) TFR(15) TFR(26) TFR(6)   x0 += k1; x1 += k2 + 1u;
  TFR(17) TFR(29) TFR(16) TFR(24)  x0 += k2; x1 += k0 + 2u;
  TFR(13) TFR(15) TFR(26) TFR(6)   x0 += k0; x1 += k1 + 3u;
  TFR(17) TFR(29) TFR(16) TFR(24)  x0 += k1; x1 += k2 + 4u;
  TFR(13) TFR(15) TFR(26) TFR(6)   x0 += k2; x1 += k0 + 5u;
#undef TFR
  o0 = x0; o1 = x1;
}

// ---------- conversion / padding ----------
__global__ __launch_bounds__(256)
void cvt_bf16(const float* __restrict__ s, u16* __restrict__ d, int n4) {
  const int i = blockIdx.x * 256 + threadIdx.x;
  if (i >= n4) return;
  const float4 v = ((const float4*)s)[i];
  ushort4 o;
  o.x = f2bf(v.x); o.y = f2bf(v.y); o.z = f2bf(v.z); o.w = f2bf(v.w);
  ((ushort4*)d)[i] = o;
}

__global__ __launch_bounds__(256)
void pad_cls(const float* __restrict__ src, u16* __restrict__ dst) {
  const int i = blockIdx.x * 256 + threadIdx.x;      // 32*2048
  const int row = i >> 11, col = i & 2047;
  dst[i] = (row < 21) ? f2bf(src[row * 2048 + col]) : (u16)0;
}

__global__ __launch_bounds__(256)
void pad_head(const float* __restrict__ cf, const float* __restrict__ mk,
              u16* __restrict__ dst) {
  const int i = blockIdx.x * 256 + threadIdx.x;      // 32*1024
  const int row = i >> 10, col = i & 1023;
  float v = 0.0f;
  if (row < 22)      v = cf[row * 1024 + col];
  else if (row < 24) v = mk[(row - 22) * 1024 + col];
  dst[i] = f2bf(v);
}

// zero h buffer (t=0 reads it) + the 4 group-barrier counters (ws is poisoned
// 0xAA before every timed launch, so re-init every call)
__global__ __launch_bounds__(256)
void init_h(u16* __restrict__ hbf, u32* __restrict__ barrier_cnt) {
  const int i = blockIdx.x * 256 + threadIdx.x;      // 128*1024
  hbf[i] = 0;
  if (i < 4) barrier_cnt[i * 64] = 0u;               // counters 256 B apart
}

// ---------- big GEMM: C[M,N] = A[M,K] * B[N,K]^T (+bias, opt relu) ----------
// 128x128 tile, BK=64, 256 threads (4 waves as 2x2 of 64x64)
template<int RELU>
__global__ __launch_bounds__(256)
void gemm128(const u16* __restrict__ A, const u16* __restrict__ Bw,
             const float* __restrict__ bias, float* __restrict__ C,
             int N, int K) {
  __shared__ __align__(16) u16 As[128 * 64];
  __shared__ __align__(16) u16 Bs[128 * 64];
  const int tid = threadIdx.x;
  const int wv = tid >> 6, lane = tid & 63;
  const int wm = wv >> 1, wn = wv & 1;
  const u16* Ab = A + (size_t)blockIdx.x * 128 * K;
  const u16* Bb = Bw + (size_t)blockIdx.y * 128 * K;
  const int lr = lane >> 3, lc = lane & 7;
  f4_t acc[4][4] = {};
  for (int k0 = 0; k0 < K; k0 += 64) {
#pragma unroll
    for (int i = 0; i < 4; ++i) {
      const int row = wv * 32 + i * 8;
      cp16(Ab + (size_t)(row + lr) * K + (k0 + lc * 8), &As[row * 64]);
      cp16(Bb + (size_t)(row + lr) * K + (k0 + lc * 8), &Bs[row * 64]);
    }
    __syncthreads();
#pragma unroll
    for (int kk = 0; kk < 2; ++kk) {
      bf8_t av[4], bv[4];
#pragma unroll
      for (int mt = 0; mt < 4; ++mt)
        av[mt] = *(const bf8_t*)&As[(wm * 64 + mt * 16 + (lane & 15)) * 64 + kk * 32 + (lane >> 4) * 8];
#pragma unroll
      for (int nt = 0; nt < 4; ++nt)
        bv[nt] = *(const bf8_t*)&Bs[(wn * 64 + nt * 16 + (lane & 15)) * 64 + kk * 32 + (lane >> 4) * 8];
#pragma unroll
      for (int mt = 0; mt < 4; ++mt)
#pragma unroll
        for (int nt = 0; nt < 4; ++nt)
          acc[mt][nt] = __builtin_amdgcn_mfma_f32_16x16x32_bf16(av[mt], bv[nt], acc[mt][nt], 0, 0, 0);
    }
    __syncthreads();
  }
  const int q = lane >> 4, cn = lane & 15;
#pragma unroll
  for (int mt = 0; mt < 4; ++mt) {
#pragma unroll
    for (int nt = 0; nt < 4; ++nt) {
      const int col = blockIdx.y * 128 + wn * 64 + nt * 16 + cn;
      const float bb = bias[col];
#pragma unroll
      for (int r = 0; r < 4; ++r) {
        const int row = blockIdx.x * 128 + wm * 64 + mt * 16 + q * 4 + r;
        float v = acc[mt][nt][r] + bb;
        if (RELU) v = fmaxf(v, 0.0f);
        C[(size_t)row * N + col] = v;
      }
    }
  }
}

// ---------- skinny GEMM: C[M,32] = A[M,K] * B[32,K]^T, M-tile 64 ----------
// HEAD=0: vl_preds (cols<21, +cls_b). HEAD=1: enc (cols<22,+cf_b) / mask (cols 22..23,+mk_b)
template<int HEAD>
__global__ __launch_bounds__(256)
void gemm_skinny(const u16* __restrict__ A, const u16* __restrict__ Bw,
                 const float* __restrict__ bias, const float* __restrict__ bias2,
                 float* __restrict__ C0, float* __restrict__ C1, int K) {
  __shared__ __align__(16) u16 As[64 * 64];
  __shared__ __align__(16) u16 Bs[32 * 64];
  const int tid = threadIdx.x, wv = tid >> 6, lane = tid & 63;
  const u16* Ab = A + (size_t)blockIdx.x * 64 * K;
  const int lr = lane >> 3, lc = lane & 7;
  f4_t acc[2] = {};
  for (int k0 = 0; k0 < K; k0 += 64) {
#pragma unroll
    for (int i = 0; i < 2; ++i) {
      const int row = wv * 16 + i * 8;
      cp16(Ab + (size_t)(row + lr) * K + (k0 + lc * 8), &As[row * 64]);
    }
    {
      const int row = wv * 8;
      cp16(Bw + (size_t)(row + lr) * K + (k0 + lc * 8), &Bs[row * 64]);
    }
    __syncthreads();
#pragma unroll
    for (int kk = 0; kk < 2; ++kk) {
      bf8_t a = *(const bf8_t*)&As[(wv * 16 + (lane & 15)) * 64 + kk * 32 + (lane >> 4) * 8];
#pragma unroll
      for (int nt = 0; nt < 2; ++nt) {
        bf8_t b = *(const bf8_t*)&Bs[(nt * 16 + (lane & 15)) * 64 + kk * 32 + (lane >> 4) * 8];
        acc[nt] = __builtin_amdgcn_mfma_f32_16x16x32_bf16(a, b, acc[nt], 0, 0, 0);
      }
    }
    __syncthreads();
  }
  const int q = lane >> 4, cn = lane & 15;
#pragma unroll
  for (int nt = 0; nt < 2; ++nt) {
    const int col = nt * 16 + cn;
#pragma unroll
    for (int r = 0; r < 4; ++r) {
      const int row = blockIdx.x * 64 + wv * 16 + q * 4 + r;
      const float v = acc[nt][r];
      if (HEAD) {
        if (col < 22)      C0[(size_t)row * 22 + col] = v + bias[col];
        else if (col < 24) C1[(size_t)row * 2 + (col - 22)] = v + bias2[col - 22];
      } else {
        if (col < 21)      C0[(size_t)row * 21 + col] = v + bias[col];
      }
    }
  }
}

// ---------- dropout: JAX partitionable threefry bernoulli, key 42, p_keep=0.7 ----------
// bits = o0 ^ o1 of threefry2x32((0,42), (0, j))  [verified R3: absmax 0.031 PASS]
__global__ __launch_bounds__(256)
void dropout_kernel(float* __restrict__ x, u16* __restrict__ xbf) {
  const u32 tid = blockIdx.x * 256u + threadIdx.x;   // 2^22 threads
  const u32 j0 = tid * 4u;
  float4 a = *(const float4*)(x + j0);
  float av[4] = {a.x, a.y, a.z, a.w};
  u16 abf[4];
#pragma unroll
  for (int i = 0; i < 4; ++i) {
    u32 o0, o1;
    threefry_0_42(0u, j0 + (u32)i, o0, o1);
    const u32 bits = o0 ^ o1;
    const float u1 = __uint_as_float((bits >> 9) | 0x3f800000u) - 1.0f;
    av[i] = (u1 < 0.7f) ? av[i] * (1.0f / 0.7f) : 0.0f;
    abf[i] = f2bf(av[i]);
  }
  float4 oa; oa.x = av[0]; oa.y = av[1]; oa.z = av[2]; oa.w = av[3];
  *(float4*)(x + j0) = oa;
  ushort4 ua; ua.x = abf[0]; ua.y = abf[1]; ua.z = abf[2]; ua.w = abf[3];
  *(ushort4*)(xbf + j0) = ua;
}

// ---------- persistent GRU v2: all 64 steps in ONE kernel ----------
// 256 blocks x 256 threads, 1 block/CU (LDS ~124 KB), all co-resident.
// Block (cb = blockIdx.x & 63, sb = blockIdx.x >> 6): 16 hid cols, 32 seqs.
// h rows are block-diagonal in sb -> only the 64 blocks sharing sb must sync:
// 4 INDEPENDENT group barriers (counters 256 B apart).  [R4 post-mortem: one
// 256-wide barrier + acquire-per-poll (XCD cache inv per poll) = 22.8 us/step]
// v2: relaxed poll + single acquire at exit; gi(t+1) prefetched into regs
// BEFORE the barrier (gi is h-independent); all 16 h-frag loads issued as one
// burst so L3 latency is paid once.
#define GRU_BLOCKS 256
__global__ __launch_bounds__(256, 1)
void gru_persistent(const u16* __restrict__ whh, const float* __restrict__ gi,
                    const float* __restrict__ bhh, u16* __restrict__ hbuf0,
                    u16* __restrict__ hbuf1, u16* __restrict__ hrbf,
                    u32* barrier_cnt) {
  __shared__ __align__(16) u16 Ws[48 * 1032];        // 99,072 B
  __shared__ float Gs[4][32 * 49];                   // 25,088 B
  const int tid = threadIdx.x, wv = tid >> 6, lane = tid & 63;
  const int cb = blockIdx.x & 63, sb = blockIdx.x >> 6;
  const int col0 = cb * 16, seq0 = sb * 32;
  u32* const cnt = barrier_cnt + sb * 64;            // per-group counter

  // ---- stage whh slab (local rows: 0-15 r-gate, 16-31 z, 32-47 n) ----
  for (int i = tid; i < 48 * 128; i += 256) {        // 16B chunks
    const int row = i >> 7, ch = i & 127;
    const int grow = (row >> 4) * 1024 + col0 + (row & 15);
    const uint4 v = *(const uint4*)(whh + (size_t)grow * 1024 + ch * 8);
    *(uint4*)&Ws[row * 1032 + ch * 8] = v;
  }

  // ---- per-thread persistent state ----
  const int j = tid & 15;                            // col within tile
  const int mA = tid >> 4, mB = 16 + (tid >> 4);     // two seq rows
  const int col = col0 + j;
  const int seqA = seq0 + mA, seqB = seq0 + mB;
  float hA = 0.0f, hB = 0.0f;                        // fp32 h master copy (regs)
  const float bR = bhh[col], bZ = bhh[1024 + col], bN = bhh[2048 + col];
  const size_t gbA = ((size_t)((seqA >> 3) * 512 + (seqA & 7) * 64)) * 3072 + col;
  const size_t gbB = ((size_t)((seqB >> 3) * 512 + (seqB & 7) * 64)) * 3072 + col;
  const int la15 = lane & 15, la16 = lane >> 4;
  // gi prefetch registers (step t values loaded during step t-1)
  float giA0, giA1, giA2, giB0, giB1, giB2;
  {
    giA0 = gi[gbA]; giA1 = gi[gbA + 1024]; giA2 = gi[gbA + 2048];
    giB0 = gi[gbB]; giB1 = gi[gbB + 1024]; giB2 = gi[gbB + 2048];
  }
  __syncthreads();

  for (int t = 0; t < 64; ++t) {
    const u16* __restrict__ hread = (t & 1) ? hbuf1 : hbuf0;
    u16* __restrict__ hwrite      = (t & 1) ? hbuf0 : hbuf1;
    // ---- burst-load all h fragments (L3 latency paid once) ----
    const int kbase = wv * 256;
    bf8_t a0v[8], a1v[8];
#pragma unroll
    for (int kc = 0; kc < 8; ++kc) {
      const int k = kbase + kc * 32 + la16 * 8;
      a0v[kc] = *(const bf8_t*)(hread + (size_t)(seq0 + la15) * 1024 + k);
      a1v[kc] = *(const bf8_t*)(hread + (size_t)(seq0 + 16 + la15) * 1024 + k);
    }
    // ---- G partial = h[32 x k-slice] @ Ws^T, K split across waves ----
    f4_t acc[2][3] = {};
#pragma unroll
    for (int kc = 0; kc < 8; ++kc) {
      const int k = kbase + kc * 32 + la16 * 8;
#pragma unroll
      for (int nt = 0; nt < 3; ++nt) {
        bf8_t b = *(const bf8_t*)&Ws[(nt * 16 + la15) * 1032 + k];
        acc[0][nt] = __builtin_amdgcn_mfma_f32_16x16x32_bf16(a0v[kc], b, acc[0][nt], 0, 0, 0);
        acc[1][nt] = __builtin_amdgcn_mfma_f32_16x16x32_bf16(a1v[kc], b, acc[1][nt], 0, 0, 0);
      }
    }
    // ---- stash partials (C layout: col=lane&15, row=quad*4+r) ----
#pragma unroll
    for (int mt = 0; mt < 2; ++mt)
#pragma unroll
      for (int nt = 0; nt < 3; ++nt)
#pragma unroll
        for (int r = 0; r < 4; ++r)
          Gs[wv][(mt * 16 + la16 * 4 + r) * 49 + nt * 16 + la15] = acc[mt][nt][r];
    __syncthreads();
    // ---- reduce 4 wave-partials + gate math, 2 (seq,col) items/thread ----
#pragma unroll
    for (int p = 0; p < 2; ++p) {
      const int m = p ? mB : mA;
      float Gr = Gs[0][m * 49 + j]      + Gs[1][m * 49 + j]      + Gs[2][m * 49 + j]      + Gs[3][m * 49 + j];
      float Gz = Gs[0][m * 49 + 16 + j] + Gs[1][m * 49 + 16 + j] + Gs[2][m * 49 + 16 + j] + Gs[3][m * 49 + 16 + j];
      float Gn = Gs[0][m * 49 + 32 + j] + Gs[1][m * 49 + 32 + j] + Gs[2][m * 49 + 32 + j] + Gs[3][m * 49 + 32 + j];
      const float gr = Gr + bR + (p ? giB0 : giA0);
      const float gz = Gz + bZ + (p ? giB1 : giA1);
      const float gh = Gn + bN;                      // b_hh on n-gate is scaled by r
      const float gn = (p ? giB2 : giA2);
      const float rr = 1.0f / (1.0f + __expf(-gr));
      const float zz = 1.0f / (1.0f + __expf(-gz));
      float targ = gn + rr * gh;
      targ = fminf(fmaxf(targ, -15.0f), 15.0f);
      const float e2 = __expf(2.0f * targ);
      const float nn = (e2 - 1.0f) / (e2 + 1.0f);
      const float hp = p ? hB : hA;
      const float h = (1.0f - zz) * nn + zz * hp;
      if (p) hB = h; else hA = h;
      const int seq = p ? seqB : seqA;
      hwrite[(size_t)seq * 1024 + col] = f2bf(h);
      hrbf[((size_t)t * 128 + seq) * 1024 + col] = f2bf(fmaxf(h, 0.0f));
    }
    // ---- prefetch gi for step t+1 (independent of the barrier) ----
    if (t < 63) {
      const size_t ga = gbA + (size_t)(t + 1) * 3072;
      const size_t gb = gbB + (size_t)(t + 1) * 3072;
      giA0 = gi[ga]; giA1 = gi[ga + 1024]; giA2 = gi[ga + 2048];
      giB0 = gi[gb]; giB1 = gi[gb + 1024]; giB2 = gi[gb + 2048];
    }
    // ---- group barrier: 64 blocks sharing sb; relaxed poll, acquire once ----
    __syncthreads();
    if (t < 63) {
      if (tid == 0) {
        __hip_atomic_fetch_add(cnt, 1u, __ATOMIC_RELEASE, __HIP_MEMORY_SCOPE_AGENT);
        const u32 target = (u32)(t + 1) * 64u;
        u32 v;
        do {
          while (__hip_atomic_load(cnt, __ATOMIC_RELAXED, __HIP_MEMORY_SCOPE_AGENT) < target)
            __builtin_amdgcn_s_sleep(1);
          v = __hip_atomic_load(cnt, __ATOMIC_ACQUIRE, __HIP_MEMORY_SCOPE_AGENT);
        } while (v < target);
      }
      __syncthreads();
    }
  }
}

// ---------- host ----------
extern "C" void kernel_launch(void* const* d_in, const int* in_sizes, int n_in,
                              void* d_out, int out_size, void* d_ws, size_t ws_size,
                              hipStream_t stream) {
  const float* feats = (const float*)d_in[0];
  const float* fc_w  = (const float*)d_in[1];
  const float* fc_b  = (const float*)d_in[2];
  const float* cls_w = (const float*)d_in[3];
  const float* cls_b = (const float*)d_in[4];
  const float* w_ih  = (const float*)d_in[5];
  const float* w_hh  = (const float*)d_in[6];
  const float* b_ih  = (const float*)d_in[7];
  const float* b_hh  = (const float*)d_in[8];
  const float* cf_w  = (const float*)d_in[9];
  const float* cf_b  = (const float*)d_in[10];
  const float* mk_w  = (const float*)d_in[11];
  const float* mk_b  = (const float*)d_in[12];

  char* ws = (char*)d_ws;
  size_t off = 0;
  auto alloc = [&](size_t b) { char* p = ws + off; off += (b + 255) & ~(size_t)255; return p; };
  u16*  featsbf = (u16*)alloc((size_t)8192 * 2048 * 2);
  u16*  xbf     = featsbf;                 // alias: feats_bf dead after fc GEMM
  u16*  fcwbf   = (u16*)alloc((size_t)2048 * 2048 * 2);
  u16*  wihbf   = (u16*)alloc((size_t)3072 * 2048 * 2);
  u16*  whhbf   = (u16*)alloc((size_t)3072 * 1024 * 2);
  u16*  clsp    = (u16*)alloc((size_t)32 * 2048 * 2);
  u16*  headp   = (u16*)alloc((size_t)32 * 1024 * 2);
  float* gi     = (float*)alloc((size_t)8192 * 3072 * 4);
  u16*  hbf0    = (u16*)alloc((size_t)128 * 1024 * 2);
  u16*  hbf1    = (u16*)alloc((size_t)128 * 1024 * 2);
  u16*  hrbf    = (u16*)alloc((size_t)8192 * 1024 * 2);
  u32*  barrier = (u32*)alloc(1024);                 // 4 counters, 256 B apart

  float* out_enc  = (float*)d_out;                       // [8192,22]
  float* out_mask = out_enc + (size_t)8192 * 22;         // [8192,2]
  float* out_x    = out_mask + (size_t)8192 * 2;         // [16,512,2048]
  float* out_vl   = out_x + (size_t)8192 * 2048;         // [16,512,21]

  cvt_bf16<<<16384, 256, 0, stream>>>(feats, featsbf, 4194304);
  cvt_bf16<<<4096, 256, 0, stream>>>(fc_w, fcwbf, 1048576);
  cvt_bf16<<<6144, 256, 0, stream>>>(w_ih, wihbf, 1572864);
  cvt_bf16<<<3072, 256, 0, stream>>>(w_hh, whhbf, 786432);
  pad_cls<<<256, 256, 0, stream>>>(cls_w, clsp);
  pad_head<<<128, 256, 0, stream>>>(cf_w, mk_w, headp);
  init_h<<<512, 256, 0, stream>>>(hbf0, barrier);

  // x_pre = relu(feats @ fc_w^T + fc_b) -> out_x (fp32)
  gemm128<1><<<dim3(64, 16), 256, 0, stream>>>(featsbf, fcwbf, fc_b, out_x, 2048, 2048);
  // in-place dropout on out_x; also writes bf16 x into ws
  dropout_kernel<<<16384, 256, 0, stream>>>(out_x, xbf);
  // vl_preds
  gemm_skinny<0><<<128, 256, 0, stream>>>(xbf, clsp, cls_b, nullptr, out_vl, nullptr, 2048);
  // gi = x @ w_ih^T + b_ih   (b_hh NOT folded: n-gate needs r*(gh+b_hh))
  gemm128<0><<<dim3(64, 24), 256, 0, stream>>>(xbf, wihbf, b_ih, gi, 3072, 2048);

  // all 64 GRU steps in one persistent kernel (4 independent 64-block groups)
  gru_persistent<<<GRU_BLOCKS, 256, 0, stream>>>(whhbf, gi, b_hh, hbf0, hbf1, hrbf, barrier);

  // heads: enc_scores + mask_scores
  gemm_skinny<1><<<128, 256, 0, stream>>>(hrbf, headp, cf_b, mk_b, out_enc, out_mask, 1024);
}

// Round 6
// 885.495 us; speedup vs baseline: 2.2064x; 1.5043x over previous
//
#include <hip/hip_runtime.h>
#include <stdint.h>

using u16 = unsigned short;
using u32 = unsigned int;
using u64 = unsigned long long;

typedef short bf8_t __attribute__((ext_vector_type(8)));   // 8 bf16 values (4 VGPRs)
typedef float f4_t  __attribute__((ext_vector_type(4)));

// ---------- helpers ----------
__device__ __forceinline__ u16 f2bf(float f) {
  u32 u = __float_as_uint(f);
  u32 r = (u + 0x7FFFu + ((u >> 16) & 1u)) >> 16;   // RNE
  return (u16)r;
}

__device__ __forceinline__ void cp16(const void* g, void* l) {
  // async global->LDS, 16B per lane; LDS dest = wave-uniform base + lane*16
  __builtin_amdgcn_global_load_lds(
      (const __attribute__((address_space(1))) u32*)g,
      (__attribute__((address_space(3))) u32*)l, 16, 0, 0);
}

// JAX threefry2x32, key = (0, 42)  [jax.random.key(42)]
__device__ __forceinline__ void threefry_0_42(u32 x0, u32 x1, u32& o0, u32& o1) {
  const u32 k0 = 0u, k1 = 42u;
  const u32 k2 = 0x1BD11BDAu ^ k0 ^ k1;
#define TFR(r) { x0 += x1; x1 = (x1 << r) | (x1 >> (32 - r)); x1 ^= x0; }
  x0 += k0; x1 += k1;
  TFR(13) TFR(15) TFR(26) TFR(6)   x0 += k1; x1 += k2 + 1u;
  TFR(17) TFR(29) TFR(16) TFR(24)  x0 += k2; x1 += k0 + 2u;
  TFR(13) TFR(15) TFR(26) TFR(6)   x0 += k0; x1 += k1 + 3u;
  TFR(17) TFR(29) TFR(16) TFR(24)  x0 += k1; x1 += k2 + 4u;
  TFR(13) TFR(15) TFR(26) TFR(6)   x0 += k2; x1 += k0 + 5u;
#undef TFR
  o0 = x0; o1 = x1;
}

// ---------- conversion / padding ----------
__global__ __launch_bounds__(256)
void cvt_bf16(const float* __restrict__ s, u16* __restrict__ d, int n4) {
  const int i = blockIdx.x * 256 + threadIdx.x;
  if (i >= n4) return;
  const float4 v = ((const float4*)s)[i];
  ushort4 o;
  o.x = f2bf(v.x); o.y = f2bf(v.y); o.z = f2bf(v.z); o.w = f2bf(v.w);
  ((ushort4*)d)[i] = o;
}

__global__ __launch_bounds__(256)
void pad_cls(const float* __restrict__ src, u16* __restrict__ dst) {
  const int i = blockIdx.x * 256 + threadIdx.x;      // 32*2048
  const int row = i >> 11, col = i & 2047;
  dst[i] = (row < 21) ? f2bf(src[row * 2048 + col]) : (u16)0;
}

__global__ __launch_bounds__(256)
void pad_head(const float* __restrict__ cf, const float* __restrict__ mk,
              u16* __restrict__ dst) {
  const int i = blockIdx.x * 256 + threadIdx.x;      // 32*1024
  const int row = i >> 10, col = i & 1023;
  float v = 0.0f;
  if (row < 22)      v = cf[row * 1024 + col];
  else if (row < 24) v = mk[(row - 22) * 1024 + col];
  dst[i] = f2bf(v);
}

// zero the 4 groups x 64 flag lines (256 B apart). ws is re-poisoned 0xAA before
// every timed launch -> must re-init every call. h buffers need no init: t=0
// writes before any read.
__global__ __launch_bounds__(256)
void init_flags(u32* __restrict__ flags) {
  const int i = blockIdx.x * 256 + threadIdx.x;      // 16384 u32 = 64 KB
  flags[i] = 0u;
}

// ---------- big GEMM: C[M,N] = A[M,K] * B[N,K]^T (+bias, opt relu) ----------
// 128x128 tile, BK=64, 256 threads (4 waves as 2x2 of 64x64)
template<int RELU>
__global__ __launch_bounds__(256)
void gemm128(const u16* __restrict__ A, const u16* __restrict__ Bw,
             const float* __restrict__ bias, float* __restrict__ C,
             int N, int K) {
  __shared__ __align__(16) u16 As[128 * 64];
  __shared__ __align__(16) u16 Bs[128 * 64];
  const int tid = threadIdx.x;
  const int wv = tid >> 6, lane = tid & 63;
  const int wm = wv >> 1, wn = wv & 1;
  const u16* Ab = A + (size_t)blockIdx.x * 128 * K;
  const u16* Bb = Bw + (size_t)blockIdx.y * 128 * K;
  const int lr = lane >> 3, lc = lane & 7;
  f4_t acc[4][4] = {};
  for (int k0 = 0; k0 < K; k0 += 64) {
#pragma unroll
    for (int i = 0; i < 4; ++i) {
      const int row = wv * 32 + i * 8;
      cp16(Ab + (size_t)(row + lr) * K + (k0 + lc * 8), &As[row * 64]);
      cp16(Bb + (size_t)(row + lr) * K + (k0 + lc * 8), &Bs[row * 64]);
    }
    __syncthreads();
#pragma unroll
    for (int kk = 0; kk < 2; ++kk) {
      bf8_t av[4], bv[4];
#pragma unroll
      for (int mt = 0; mt < 4; ++mt)
        av[mt] = *(const bf8_t*)&As[(wm * 64 + mt * 16 + (lane & 15)) * 64 + kk * 32 + (lane >> 4) * 8];
#pragma unroll
      for (int nt = 0; nt < 4; ++nt)
        bv[nt] = *(const bf8_t*)&Bs[(wn * 64 + nt * 16 + (lane & 15)) * 64 + kk * 32 + (lane >> 4) * 8];
#pragma unroll
      for (int mt = 0; mt < 4; ++mt)
#pragma unroll
        for (int nt = 0; nt < 4; ++nt)
          acc[mt][nt] = __builtin_amdgcn_mfma_f32_16x16x32_bf16(av[mt], bv[nt], acc[mt][nt], 0, 0, 0);
    }
    __syncthreads();
  }
  const int q = lane >> 4, cn = lane & 15;
#pragma unroll
  for (int mt = 0; mt < 4; ++mt) {
#pragma unroll
    for (int nt = 0; nt < 4; ++nt) {
      const int col = blockIdx.y * 128 + wn * 64 + nt * 16 + cn;
      const float bb = bias[col];
#pragma unroll
      for (int r = 0; r < 4; ++r) {
        const int row = blockIdx.x * 128 + wm * 64 + mt * 16 + q * 4 + r;
        float v = acc[mt][nt][r] + bb;
        if (RELU) v = fmaxf(v, 0.0f);
        C[(size_t)row * N + col] = v;
      }
    }
  }
}

// ---------- skinny GEMM: C[M,32] = A[M,K] * B[32,K]^T, M-tile 64 ----------
// HEAD=0: vl_preds (cols<21, +cls_b). HEAD=1: enc (cols<22,+cf_b) / mask (cols 22..23,+mk_b)
template<int HEAD>
__global__ __launch_bounds__(256)
void gemm_skinny(const u16* __restrict__ A, const u16* __restrict__ Bw,
                 const float* __restrict__ bias, const float* __restrict__ bias2,
                 float* __restrict__ C0, float* __restrict__ C1, int K) {
  __shared__ __align__(16) u16 As[64 * 64];
  __shared__ __align__(16) u16 Bs[32 * 64];
  const int tid = threadIdx.x, wv = tid >> 6, lane = tid & 63;
  const u16* Ab = A + (size_t)blockIdx.x * 64 * K;
  const int lr = lane >> 3, lc = lane & 7;
  f4_t acc[2] = {};
  for (int k0 = 0; k0 < K; k0 += 64) {
#pragma unroll
    for (int i = 0; i < 2; ++i) {
      const int row = wv * 16 + i * 8;
      cp16(Ab + (size_t)(row + lr) * K + (k0 + lc * 8), &As[row * 64]);
    }
    {
      const int row = wv * 8;
      cp16(Bw + (size_t)(row + lr) * K + (k0 + lc * 8), &Bs[row * 64]);
    }
    __syncthreads();
#pragma unroll
    for (int kk = 0; kk < 2; ++kk) {
      bf8_t a = *(const bf8_t*)&As[(wv * 16 + (lane & 15)) * 64 + kk * 32 + (lane >> 4) * 8];
#pragma unroll
      for (int nt = 0; nt < 2; ++nt) {
        bf8_t b = *(const bf8_t*)&Bs[(nt * 16 + (lane & 15)) * 64 + kk * 32 + (lane >> 4) * 8];
        acc[nt] = __builtin_amdgcn_mfma_f32_16x16x32_bf16(a, b, acc[nt], 0, 0, 0);
      }
    }
    __syncthreads();
  }
  const int q = lane >> 4, cn = lane & 15;
#pragma unroll
  for (int nt = 0; nt < 2; ++nt) {
    const int col = nt * 16 + cn;
#pragma unroll
    for (int r = 0; r < 4; ++r) {
      const int row = blockIdx.x * 64 + wv * 16 + q * 4 + r;
      const float v = acc[nt][r];
      if (HEAD) {
        if (col < 22)      C0[(size_t)row * 22 + col] = v + bias[col];
        else if (col < 24) C1[(size_t)row * 2 + (col - 22)] = v + bias2[col - 22];
      } else {
        if (col < 21)      C0[(size_t)row * 21 + col] = v + bias[col];
      }
    }
  }
}

// ---------- dropout: JAX partitionable threefry bernoulli, key 42, p_keep=0.7 ----------
// bits = o0 ^ o1 of threefry2x32((0,42), (0, j))  [verified R3: absmax 0.031 PASS]
__global__ __launch_bounds__(256)
void dropout_kernel(float* __restrict__ x, u16* __restrict__ xbf) {
  const u32 tid = blockIdx.x * 256u + threadIdx.x;   // 2^22 threads
  const u32 j0 = tid * 4u;
  float4 a = *(const float4*)(x + j0);
  float av[4] = {a.x, a.y, a.z, a.w};
  u16 abf[4];
#pragma unroll
  for (int i = 0; i < 4; ++i) {
    u32 o0, o1;
    threefry_0_42(0u, j0 + (u32)i, o0, o1);
    const u32 bits = o0 ^ o1;
    const float u1 = __uint_as_float((bits >> 9) | 0x3f800000u) - 1.0f;
    av[i] = (u1 < 0.7f) ? av[i] * (1.0f / 0.7f) : 0.0f;
    abf[i] = f2bf(av[i]);
  }
  float4 oa; oa.x = av[0]; oa.y = av[1]; oa.z = av[2]; oa.w = av[3];
  *(float4*)(x + j0) = oa;
  ushort4 ua; ua.x = abf[0]; ua.y = abf[1]; ua.z = abf[2]; ua.w = abf[3];
  *(ushort4*)(xbf + j0) = ua;
}

// ---------- persistent GRU v3: fence-free LLC-coherent sync ----------
// 256 blocks x 256 threads, 1 block/CU, all co-resident.
// Block (cb, sb): 16 hid cols, 32 seqs. whh slab in LDS once.
// Cross-block h + flags move as AGENT-scope RELAXED atomics (sc1 -> LLC
// coherent): no release-wbl2, no acquire-inv per step. [R5 post-mortem:
// counter-RMW arrival serialization + per-step L2 wb/inv = 13.4 us/step.]
// Ordering: h atomic stores -> per-wave s_waitcnt(0) -> __syncthreads ->
// tid0 STORES its own flag line (no RMW). Wave0's 64 lanes poll the 64
// group flags in parallel; hrbf stores + gi prefetch overlap the poll.
#define GRU_BLOCKS 256
__global__ __launch_bounds__(256, 1)
void gru_persistent(const u16* __restrict__ whh, const float* __restrict__ gi,
                    const float* __restrict__ bhh, u16* __restrict__ hbuf0,
                    u16* __restrict__ hbuf1, u16* __restrict__ hrbf,
                    u32* flags) {
  __shared__ __align__(16) u16 Ws[48 * 1032];        // 99,072 B
  __shared__ float Gs[4][32 * 50];                   // 25,600 B (pad 50: float2-aligned)
  const int tid = threadIdx.x, wv = tid >> 6, lane = tid & 63;
  const int cb = blockIdx.x & 63, sb = blockIdx.x >> 6;
  const int col0 = cb * 16, seq0 = sb * 32;
  u32* const grp_flags = flags + sb * 4096;          // 64 flags, 256 B apart
  u32* const my_flag = grp_flags + cb * 64;

  // ---- stage whh slab (local rows: 0-15 r-gate, 16-31 z, 32-47 n) ----
  for (int i = tid; i < 48 * 128; i += 256) {        // 16B chunks
    const int row = i >> 7, ch = i & 127;
    const int grow = (row >> 4) * 1024 + col0 + (row & 15);
    const uint4 v = *(const uint4*)(whh + (size_t)grow * 1024 + ch * 8);
    *(uint4*)&Ws[row * 1032 + ch * 8] = v;
  }

  // ---- per-thread persistent state: 1 seq x 2 adjacent cols ----
  const int j2 = (tid & 7) * 2;                      // even col within tile
  const int m = tid >> 3;                            // seq within tile (0..31)
  const int colA = col0 + j2;
  const int seq = seq0 + m;
  float h0 = 0.0f, h1 = 0.0f;                        // fp32 h master copy (regs)
  const float2 bR = *(const float2*)(bhh + colA);
  const float2 bZ = *(const float2*)(bhh + 1024 + colA);
  const float2 bN = *(const float2*)(bhh + 2048 + colA);
  const size_t gb0 = ((size_t)((seq >> 3) * 512 + (seq & 7) * 64)) * 3072 + colA;
  const int la15 = lane & 15, la16 = lane >> 4;
  const int kb = wv * 256 + la16 * 8;                // this wave's K slice base
  // gi prefetch registers (step t loaded during step t-1)
  float2 giR = *(const float2*)(gi + gb0);
  float2 giZ = *(const float2*)(gi + gb0 + 1024);
  float2 giN = *(const float2*)(gi + gb0 + 2048);
  __syncthreads();

  for (int t = 0; t < 64; ++t) {
    u16* __restrict__ hwrite = (t & 1) ? hbuf0 : hbuf1;
    float Gr0 = 0.f, Gr1 = 0.f, Gz0 = 0.f, Gz1 = 0.f, Gn0 = 0.f, Gn1 = 0.f;
    if (t > 0) {
      const u16* __restrict__ hread = (t & 1) ? hbuf1 : hbuf0;
      // ---- burst-load h fragments as LLC-coherent u64 atomics ----
      union FU { bf8_t v; u64 q[2]; };
      FU a0v[8], a1v[8];
#pragma unroll
      for (int kc = 0; kc < 8; ++kc) {
        const int k = kb + kc * 32;
        u64* p0 = (u64*)(hread + (size_t)(seq0 + la15) * 1024 + k);
        u64* p1 = (u64*)(hread + (size_t)(seq0 + 16 + la15) * 1024 + k);
        a0v[kc].q[0] = __hip_atomic_load(p0,     __ATOMIC_RELAXED, __HIP_MEMORY_SCOPE_AGENT);
        a0v[kc].q[1] = __hip_atomic_load(p0 + 1, __ATOMIC_RELAXED, __HIP_MEMORY_SCOPE_AGENT);
        a1v[kc].q[0] = __hip_atomic_load(p1,     __ATOMIC_RELAXED, __HIP_MEMORY_SCOPE_AGENT);
        a1v[kc].q[1] = __hip_atomic_load(p1 + 1, __ATOMIC_RELAXED, __HIP_MEMORY_SCOPE_AGENT);
      }
      // ---- G partial = h[32 x k-slice] @ Ws^T ----
      f4_t acc[2][3] = {};
#pragma unroll
      for (int kc = 0; kc < 8; ++kc) {
        const int k = kb + kc * 32;
#pragma unroll
        for (int nt = 0; nt < 3; ++nt) {
          bf8_t b = *(const bf8_t*)&Ws[(nt * 16 + la15) * 1032 + k];
          acc[0][nt] = __builtin_amdgcn_mfma_f32_16x16x32_bf16(a0v[kc].v, b, acc[0][nt], 0, 0, 0);
          acc[1][nt] = __builtin_amdgcn_mfma_f32_16x16x32_bf16(a1v[kc].v, b, acc[1][nt], 0, 0, 0);
        }
      }
      // ---- stash partials (C layout: col=lane&15, row=quad*4+r) ----
#pragma unroll
      for (int mt = 0; mt < 2; ++mt)
#pragma unroll
        for (int nt = 0; nt < 3; ++nt)
#pragma unroll
          for (int r = 0; r < 4; ++r)
            Gs[wv][(mt * 16 + la16 * 4 + r) * 50 + nt * 16 + la15] = acc[mt][nt][r];
      __syncthreads();
      // ---- reduce 4 wave-partials (float2 per gate) ----
#pragma unroll
      for (int w = 0; w < 4; ++w) {
        const float2 r2 = *(const float2*)&Gs[w][m * 50 + j2];
        const float2 z2 = *(const float2*)&Gs[w][m * 50 + 16 + j2];
        const float2 n2 = *(const float2*)&Gs[w][m * 50 + 32 + j2];
        Gr0 += r2.x; Gr1 += r2.y; Gz0 += z2.x; Gz1 += z2.y; Gn0 += n2.x; Gn1 += n2.y;
      }
    }
    // ---- gate math (2 cols) ----
    const float gr0 = Gr0 + bR.x + giR.x, gr1 = Gr1 + bR.y + giR.y;
    const float gz0 = Gz0 + bZ.x + giZ.x, gz1 = Gz1 + bZ.y + giZ.y;
    const float gh0 = Gn0 + bN.x,         gh1 = Gn1 + bN.y;   // b_hh on n-gate scaled by r
    const float rr0 = 1.0f / (1.0f + __expf(-gr0)), rr1 = 1.0f / (1.0f + __expf(-gr1));
    const float zz0 = 1.0f / (1.0f + __expf(-gz0)), zz1 = 1.0f / (1.0f + __expf(-gz1));
    float tg0 = giN.x + rr0 * gh0, tg1 = giN.y + rr1 * gh1;
    tg0 = fminf(fmaxf(tg0, -15.0f), 15.0f);
    tg1 = fminf(fmaxf(tg1, -15.0f), 15.0f);
    const float e20 = __expf(2.0f * tg0), e21 = __expf(2.0f * tg1);
    const float nn0 = (e20 - 1.0f) / (e20 + 1.0f), nn1 = (e21 - 1.0f) / (e21 + 1.0f);
    h0 = (1.0f - zz0) * nn0 + zz0 * h0;
    h1 = (1.0f - zz1) * nn1 + zz1 * h1;
    // ---- h store: one u32 agent-scope atomic (write-through to LLC) ----
    const u32 hpack = (u32)f2bf(h0) | ((u32)f2bf(h1) << 16);
    __hip_atomic_store((u32*)(hwrite + (size_t)seq * 1024 + colA), hpack,
                       __ATOMIC_RELAXED, __HIP_MEMORY_SCOPE_AGENT);
    const u32 hrpack = (u32)f2bf(fmaxf(h0, 0.0f)) | ((u32)f2bf(fmaxf(h1, 0.0f)) << 16);
    if (t < 63) {
      // ---- arrival: drain this wave's h stores, block-sync, store flag ----
      __builtin_amdgcn_s_waitcnt(0);
      __syncthreads();
      if (tid == 0)
        __hip_atomic_store(my_flag, (u32)(t + 1), __ATOMIC_RELAXED, __HIP_MEMORY_SCOPE_AGENT);
    }
    // ---- hrbf store + gi prefetch overlap the poll window ----
    *(u32*)(hrbf + ((size_t)t * 128 + seq) * 1024 + colA) = hrpack;
    if (t < 63) {
      const size_t g = gb0 + (size_t)(t + 1) * 3072;
      giR = *(const float2*)(gi + g);
      giZ = *(const float2*)(gi + g + 1024);
      giN = *(const float2*)(gi + g + 2048);
      // ---- wave0 polls all 64 group flags in parallel ----
      if (wv == 0) {
        u32* fl = grp_flags + lane * 64;
        const u32 target = (u32)(t + 1);
        while (true) {
          const u32 v = __hip_atomic_load(fl, __ATOMIC_RELAXED, __HIP_MEMORY_SCOPE_AGENT);
          if (__ballot(v >= target) == ~0ull) break;
          __builtin_amdgcn_s_sleep(1);
        }
      }
      __syncthreads();
    }
  }
}

// ---------- host ----------
extern "C" void kernel_launch(void* const* d_in, const int* in_sizes, int n_in,
                              void* d_out, int out_size, void* d_ws, size_t ws_size,
                              hipStream_t stream) {
  const float* feats = (const float*)d_in[0];
  const float* fc_w  = (const float*)d_in[1];
  const float* fc_b  = (const float*)d_in[2];
  const float* cls_w = (const float*)d_in[3];
  const float* cls_b = (const float*)d_in[4];
  const float* w_ih  = (const float*)d_in[5];
  const float* w_hh  = (const float*)d_in[6];
  const float* b_ih  = (const float*)d_in[7];
  const float* b_hh  = (const float*)d_in[8];
  const float* cf_w  = (const float*)d_in[9];
  const float* cf_b  = (const float*)d_in[10];
  const float* mk_w  = (const float*)d_in[11];
  const float* mk_b  = (const float*)d_in[12];

  char* ws = (char*)d_ws;
  size_t off = 0;
  auto alloc = [&](size_t b) { char* p = ws + off; off += (b + 255) & ~(size_t)255; return p; };
  u16*  featsbf = (u16*)alloc((size_t)8192 * 2048 * 2);
  u16*  xbf     = featsbf;                 // alias: feats_bf dead after fc GEMM
  u16*  fcwbf   = (u16*)alloc((size_t)2048 * 2048 * 2);
  u16*  wihbf   = (u16*)alloc((size_t)3072 * 2048 * 2);
  u16*  whhbf   = (u16*)alloc((size_t)3072 * 1024 * 2);
  u16*  clsp    = (u16*)alloc((size_t)32 * 2048 * 2);
  u16*  headp   = (u16*)alloc((size_t)32 * 1024 * 2);
  float* gi     = (float*)alloc((size_t)8192 * 3072 * 4);
  u16*  hbf0    = (u16*)alloc((size_t)128 * 1024 * 2);
  u16*  hbf1    = (u16*)alloc((size_t)128 * 1024 * 2);
  u16*  hrbf    = (u16*)alloc((size_t)8192 * 1024 * 2);
  u32*  flags   = (u32*)alloc(16384 * 4);            // 4 groups x 64 flags x 256 B

  float* out_enc  = (float*)d_out;                       // [8192,22]
  float* out_mask = out_enc + (size_t)8192 * 22;         // [8192,2]
  float* out_x    = out_mask + (size_t)8192 * 2;         // [16,512,2048]
  float* out_vl   = out_x + (size_t)8192 * 2048;         // [16,512,21]

  cvt_bf16<<<16384, 256, 0, stream>>>(feats, featsbf, 4194304);
  cvt_bf16<<<4096, 256, 0, stream>>>(fc_w, fcwbf, 1048576);
  cvt_bf16<<<6144, 256, 0, stream>>>(w_ih, wihbf, 1572864);
  cvt_bf16<<<3072, 256, 0, stream>>>(w_hh, whhbf, 786432);
  pad_cls<<<256, 256, 0, stream>>>(cls_w, clsp);
  pad_head<<<128, 256, 0, stream>>>(cf_w, mk_w, headp);
  init_flags<<<64, 256, 0, stream>>>(flags);

  // x_pre = relu(feats @ fc_w^T + fc_b) -> out_x (fp32)
  gemm128<1><<<dim3(64, 16), 256, 0, stream>>>(featsbf, fcwbf, fc_b, out_x, 2048, 2048);
  // in-place dropout on out_x; also writes bf16 x into ws
  dropout_kernel<<<16384, 256, 0, stream>>>(out_x, xbf);
  // vl_preds
  gemm_skinny<0><<<128, 256, 0, stream>>>(xbf, clsp, cls_b, nullptr, out_vl, nullptr, 2048);
  // gi = x @ w_ih^T + b_ih   (b_hh NOT folded: n-gate needs r*(gh+b_hh))
  gemm128<0><<<dim3(64, 24), 256, 0, stream>>>(xbf, wihbf, b_ih, gi, 3072, 2048);

  // all 64 GRU steps in one persistent kernel (4 independent 64-block groups)
  gru_persistent<<<GRU_BLOCKS, 256, 0, stream>>>(whhbf, gi, b_hh, hbf0, hbf1, hrbf, flags);

  // heads: enc_scores + mask_scores
  gemm_skinny<1><<<128, 256, 0, stream>>>(hrbf, headp, cf_b, mk_b, out_enc, out_mask, 1024);
}